// Round 1
// 4782.519 us; speedup vs baseline: 1.2866x; 1.2866x over previous
//
#include <hip/hip_runtime.h>
#include <stdint.h>

#define SEQ  2048
#define HID  2048
#define INP  1024
#define OUTW 512
#define SENT 0x7F7F7F7Fu   // 3.39e38f; |h|<1 so a real h word never matches

__device__ __forceinline__ unsigned short f2bf(float x){
  unsigned int u = __float_as_uint(x);
  u += 0x7fffu + ((u >> 16) & 1u);           // RNE
  return (unsigned short)(u >> 16);
}
__device__ __forceinline__ float bf_lo(unsigned int w){ return __uint_as_float(w << 16); }
__device__ __forceinline__ float bf_hi(unsigned int w){ return __uint_as_float(w & 0xffff0000u); }

// ---------------- Phase 0: sentinel-fill hist ----------------
__global__ __launch_bounds__(256)
void fill_hist(uint4* __restrict__ hist4){
  size_t i = (size_t)blockIdx.x*blockDim.x + threadIdx.x;   // 1,048,576 uint4 = 16 MB
  hist4[i] = make_uint4(SENT,SENT,SENT,SENT);
}

// ---------------- Phase A: Xproj[b][t][u][g] = W_g[j][2048:] @ x_t + b_g[j], bf16 ----------------
__global__ __launch_bounds__(256)
void xproj_gemm(const float* __restrict__ Wf, const float* __restrict__ Wi,
                const float* __restrict__ Wc, const float* __restrict__ Wo,
                const float* __restrict__ bfv, const float* __restrict__ biv,
                const float* __restrict__ bcv, const float* __restrict__ bov,
                const float* __restrict__ X, unsigned short* __restrict__ xproj)
{
  __shared__ float As[16][68];
  __shared__ float Bs[16][68];
  const int t0 = blockIdx.x * 64;
  const int r0 = blockIdx.y * 64;
  const int gate = r0 >> 11;
  const int j0 = r0 & 2047;
  const float* Wg = gate==0?Wf:gate==1?Wi:gate==2?Wc:Wo;
  const float* bg = gate==0?bfv:gate==1?biv:gate==2?bcv:bov;
  const int tid = threadIdx.x;
  const int tx = tid & 15, ty = tid >> 4;
  const int lr = tid >> 2;
  const int lk = (tid & 3) * 4;
  float acc[4][4] = {};
  for (int k0 = 0; k0 < INP; k0 += 16){
    float4 av = *(const float4*)(Wg + (size_t)(j0+lr)*3072 + 2048 + k0 + lk);
    float4 bv = *(const float4*)(X  + (size_t)(t0+lr)*INP  + k0 + lk);
    __syncthreads();
    As[lk+0][lr]=av.x; As[lk+1][lr]=av.y; As[lk+2][lr]=av.z; As[lk+3][lr]=av.w;
    Bs[lk+0][lr]=bv.x; Bs[lk+1][lr]=bv.y; Bs[lk+2][lr]=bv.z; Bs[lk+3][lr]=bv.w;
    __syncthreads();
    #pragma unroll
    for (int kk=0;kk<16;kk++){
      float a[4], bb[4];
      #pragma unroll
      for (int i=0;i<4;i++) a[i]  = As[kk][ty*4+i];
      #pragma unroll
      for (int j=0;j<4;j++) bb[j] = Bs[kk][tx*4+j];
      #pragma unroll
      for (int i=0;i<4;i++)
        #pragma unroll
        for (int j=0;j<4;j++)
          acc[i][j] = fmaf(a[i], bb[j], acc[i][j]);
    }
  }
  #pragma unroll
  for (int i=0;i<4;i++){
    int j = j0 + ty*4 + i;
    float bias = bg[j];
    int bb = j >> 3, u = j & 7;
    #pragma unroll
    for (int jj=0;jj<4;jj++){
      int t = t0 + tx*4 + jj;
      // layout: [block][t][unit][gate] so a wave's 4 gates are 4 adjacent ushorts
      size_t idx = (((size_t)bb*SEQ + t)*8 + u)*4 + gate;
      xproj[idx] = f2bf(acc[i][jj] + bias);
    }
  }
}

// ---------------- Phase B: persistent recurrent scan ----------------
// 256 blocks x 512 thr (8 waves). Wave w of block b owns hidden unit u = 8b+w,
// holding ALL FOUR gate rows (4 x 2048 fp32) in 128 VGPR/lane.
// Per step: poll h_{t-1} slice -> LDS (double-buffered) -> ONE barrier -> dot
// -> in-wave butterfly reduce (gate (lane&3) per quad) -> in-wave activations +
// cell update -> lane 0 publishes h immediately (no second barrier, no LDS gate
// exchange, no 8-thread serial section).
// h_lds double buffer proof: reads of buf p at iter t precede that wave's
// publish -> precede its iter t+1 poll -> precede its arrival at iter t+1's
// barrier; writes to buf p recur at iter t+2, after that barrier. Safe.
__global__ __launch_bounds__(512, 2)
void lstm_persistent(const float* __restrict__ Wf, const float* __restrict__ Wi,
                     const float* __restrict__ Wc, const float* __restrict__ Wo,
                     const unsigned short* __restrict__ xproj,
                     float* __restrict__ hist)          // d_out hidden region [SEQ][HID]
{
  const int b    = blockIdx.x;
  const int tid  = threadIdx.x;
  const int wv   = tid >> 6;
  const int lane = tid & 63;
  const int u    = b*8 + wv;                 // this wave's hidden unit

  __shared__ unsigned int h_lds[2][HID/2];   // packed bf16 pairs: word W = cols (2W,2W+1)

  // fp32 weights: wreg[r][kc*8+j] = W_{gate r}[u][8*lane + 512*kc + j]
  const float* const Wm[4] = {Wf, Wi, Wc, Wo};
  float wreg[4][32];
  #pragma unroll
  for (int r=0;r<4;r++){
    const float* rowp = Wm[r] + (size_t)u*3072;
    #pragma unroll
    for (int kc=0;kc<4;kc++){
      float4 f0 = *(const float4*)(rowp + 8*lane + 512*kc);
      float4 f1 = *(const float4*)(rowp + 8*lane + 512*kc + 4);
      wreg[r][kc*8+0]=f0.x; wreg[r][kc*8+1]=f0.y; wreg[r][kc*8+2]=f0.z; wreg[r][kc*8+3]=f0.w;
      wreg[r][kc*8+4]=f1.x; wreg[r][kc*8+5]=f1.y; wreg[r][kc*8+6]=f1.z; wreg[r][kc*8+7]=f1.w;
    }
  }

  float c = 0.0f;                            // cell state, redundant across lanes
  const unsigned short* xpp = xproj + (size_t)b*SEQ*32 + wv*4 + lane; // valid lane<4

  for (int t=0; t<SEQ; t++){
    // x-projection (tiny, cached) — issue before the h spin
    float xp = (lane < 4) ? bf_lo((unsigned)xpp[(size_t)t*32]) : 0.0f;

    // ---- acquire h_{t-1}: self-validating sentinel poll, LLC-scope loads ----
    uint2 pk;
    if (t == 0){
      pk.x = 0u; pk.y = 0u;                  // h_{-1} = 0 (bf16 zeros)
    } else {
      const unsigned long long* hp =
        (const unsigned long long*)(hist + (size_t)(t-1)*HID) + 2*tid;  // floats 4tid..4tid+3
      unsigned long long qa = __hip_atomic_load(hp,   __ATOMIC_RELAXED, __HIP_MEMORY_SCOPE_AGENT);
      unsigned long long qb = __hip_atomic_load(hp+1, __ATOMIC_RELAXED, __HIP_MEMORY_SCOPE_AGENT);
      int gd = 0;
      for(;;){
        bool ba = ((unsigned)qa==SENT) | ((unsigned)(qa>>32)==SENT);
        bool bb = ((unsigned)qb==SENT) | ((unsigned)(qb>>32)==SENT);
        if (!(ba|bb) || gd >= (1<<17)) break;   // guard: fail wrong, never hang
        if (ba) qa = __hip_atomic_load(hp,   __ATOMIC_RELAXED, __HIP_MEMORY_SCOPE_AGENT);
        if (bb) qb = __hip_atomic_load(hp+1, __ATOMIC_RELAXED, __HIP_MEMORY_SCOPE_AGENT);
        gd++;
      }
      unsigned a0=(unsigned)qa, a1=(unsigned)(qa>>32), a2=(unsigned)qb, a3=(unsigned)(qb>>32);
      pk.x = (a1 & 0xffff0000u) | (a0 >> 16);   // truncate-pack to bf16 pairs
      pk.y = (a3 & 0xffff0000u) | (a2 >> 16);
    }
    const int p = t & 1;
    *(uint2*)&h_lds[p][2*tid] = pk;
    __syncthreads();                          // the ONLY barrier per step

    // ---- dot: 4 gate rows x 32 cols/lane against register-resident weights ----
    float acc[4] = {0.f,0.f,0.f,0.f};
    #pragma unroll
    for (int kc=0;kc<4;kc++){
      uint4 hw = *(const uint4*)&h_lds[p][4*lane + 256*kc];   // cols 8*lane+512*kc+0..7
      float hf[8];
      hf[0]=bf_lo(hw.x); hf[1]=bf_hi(hw.x); hf[2]=bf_lo(hw.y); hf[3]=bf_hi(hw.y);
      hf[4]=bf_lo(hw.z); hf[5]=bf_hi(hw.z); hf[6]=bf_lo(hw.w); hf[7]=bf_hi(hw.w);
      #pragma unroll
      for (int r=0;r<4;r++)
        #pragma unroll
        for (int j=0;j<8;j++)
          acc[r] = fmaf(wreg[r][kc*8+j], hf[j], acc[r]);
    }

    // ---- pair-folding butterfly: lane l ends with gate (l&3) fully reduced ----
    const int b0 = lane & 1;
    const int b1 = lane & 2;
    float x01 = b0 ? acc[1] : acc[0];
    float y01 = b0 ? acc[0] : acc[1];
    x01 += __shfl_xor(y01, 1);                // even: gate0 pair-sum, odd: gate1
    float x23 = b0 ? acc[3] : acc[2];
    float y23 = b0 ? acc[2] : acc[3];
    x23 += __shfl_xor(y23, 1);                // even: gate2 pair-sum, odd: gate3
    float xk = b1 ? x23 : x01;
    float yk = b1 ? x01 : x23;
    xk += __shfl_xor(yk, 2);                  // lane (l&3)=r holds gate r over quad
    xk += __shfl_xor(xk, 4);
    xk += __shfl_xor(xk, 8);
    xk += __shfl_xor(xk, 16);
    xk += __shfl_xor(xk, 32);                 // full 64-lane sum of gate (l&3)

    // ---- activations in-wave (no divergence: shared exp + rcp form) ----
    float pre = xk + __shfl(xp, lane & 3);    // add this gate's x-projection
    const bool ist = ((lane & 3) == 2);       // gate 2 = tanh, others sigmoid
    float px = ist ? fminf(15.0f, fmaxf(-15.0f, pre)) : pre;
    float e  = __expf(ist ? -2.0f*px : -px);
    float d  = 1.0f/(1.0f + e);
    float gv = ist ? (1.0f - e)*d : d;        // tanh=(1-e)/(1+e), sigmoid=1/(1+e)

    float f  = __shfl(gv, 0);
    float ii = __shfl(gv, 1);
    float cg = __shfl(gv, 2);
    float o  = __shfl(gv, 3);

    c = fmaf(f, c, ii*cg);
    float cx = fminf(15.0f, fmaxf(-15.0f, c));
    float e2 = __expf(-2.0f*cx);
    float h  = o * (1.0f - e2)/(1.0f + e2);

    // ---- publish immediately (fire-and-forget, self-validating) ----
    if (lane == 0)
      __hip_atomic_store(hist + (size_t)t*HID + u, h,
                         __ATOMIC_RELAXED, __HIP_MEMORY_SCOPE_AGENT);
  }
}

// ---------------- Phase C: y[t][o] = W_y[o] @ h_t + b_y[o] ----------------
__global__ __launch_bounds__(256)
void ygemm(const float* __restrict__ hist, const float* __restrict__ Wy,
           const float* __restrict__ by, float* __restrict__ yout)
{
  __shared__ float As[16][68];
  __shared__ float Bs[16][68];
  const int o0 = blockIdx.x * 64;
  const int t0 = blockIdx.y * 64;
  const int tid = threadIdx.x;
  const int tx = tid & 15, ty = tid >> 4;
  const int lr = tid >> 2;
  const int lk = (tid & 3) * 4;
  float acc[4][4] = {};
  for (int k0 = 0; k0 < HID; k0 += 16){
    float4 av = *(const float4*)(hist + (size_t)(t0+lr)*HID + k0 + lk);
    float4 bv = *(const float4*)(Wy   + (size_t)(o0+lr)*HID + k0 + lk);
    __syncthreads();
    As[lk+0][lr]=av.x; As[lk+1][lr]=av.y; As[lk+2][lr]=av.z; As[lk+3][lr]=av.w;
    Bs[lk+0][lr]=bv.x; Bs[lk+1][lr]=bv.y; Bs[lk+2][lr]=bv.z; Bs[lk+3][lr]=bv.w;
    __syncthreads();
    #pragma unroll
    for (int kk=0;kk<16;kk++){
      float a[4], bb[4];
      #pragma unroll
      for (int i=0;i<4;i++) a[i]  = As[kk][ty*4+i];
      #pragma unroll
      for (int j=0;j<4;j++) bb[j] = Bs[kk][tx*4+j];
      #pragma unroll
      for (int i=0;i<4;i++)
        #pragma unroll
        for (int j=0;j<4;j++)
          acc[i][j] = fmaf(a[i], bb[j], acc[i][j]);
    }
  }
  #pragma unroll
  for (int i=0;i<4;i++){
    int t = t0 + ty*4 + i;
    #pragma unroll
    for (int jj=0;jj<4;jj++){
      int o = o0 + tx*4 + jj;
      yout[(size_t)t*OUTW + o] = acc[i][jj] + by[o];
    }
  }
}

extern "C" void kernel_launch(void* const* d_in, const int* in_sizes, int n_in,
                              void* d_out, int out_size, void* d_ws, size_t ws_size,
                              hipStream_t stream) {
  const float* X  = (const float*)d_in[0];
  const float* Wf = (const float*)d_in[1];
  const float* bf = (const float*)d_in[2];
  const float* Wi = (const float*)d_in[3];
  const float* bi = (const float*)d_in[4];
  const float* Wc = (const float*)d_in[5];
  const float* bc = (const float*)d_in[6];
  const float* Wo = (const float*)d_in[7];
  const float* bo = (const float*)d_in[8];
  const float* Wy = (const float*)d_in[9];
  const float* by = (const float*)d_in[10];

  float* yout = (float*)d_out;                       // [2048][512]
  float* hist = (float*)d_out + (size_t)SEQ*OUTW;    // [2048][2048]

  const size_t XPROJ_BYTES = (size_t)256*SEQ*32*sizeof(unsigned short); // 33,554,432
  if (ws_size < XPROJ_BYTES) return;   // clean failure instead of corruption

  unsigned short* xproj = (unsigned short*)d_ws;

  // sentinel-fill hist (16 MB); stream-ordered before the scan
  fill_hist<<<(SEQ*(size_t)HID/4)/256, 256, 0, stream>>>((uint4*)hist);

  dim3 gA(32, 128);
  xproj_gemm<<<gA, 256, 0, stream>>>(Wf,Wi,Wc,Wo, bf,bi,bc,bo, X, xproj);
  lstm_persistent<<<256, 512, 0, stream>>>(Wf,Wi,Wc,Wo, xproj, hist);
  dim3 gY(8, 32);
  ygemm<<<gY, 256, 0, stream>>>(hist, Wy, by, yout);
}